// Round 1
// baseline (337.275 us; speedup 1.0000x reference)
//
#include <hip/hip_runtime.h>
#include <math.h>

#define H 4096
#define HWORDS4 (H / 4)          // 1024 float4 per row
#define ITERS (HWORDS4 / 64)     // 16 float4 loads per lane per row

__device__ __forceinline__ float wave_reduce_sum(float v) {
    #pragma unroll
    for (int off = 32; off > 0; off >>= 1)
        v += __shfl_down(v, off, 64);
    return v;
}

__device__ __forceinline__ float sigmoidf_(float x) {
    return 1.0f / (1.0f + __expf(-x));
}

// Kernel 1: all four GEMVs + the two scalar-gate dot products.
// One wave per output row. rowId 0..16383 -> Wq/Wk/Wv/Wo rows; 16384/16385 -> wi/wf dots.
__global__ __launch_bounds__(256) void gemv_all(
    const float* __restrict__ x,
    const float* __restrict__ Wq, const float* __restrict__ Wk,
    const float* __restrict__ Wv, const float* __restrict__ Wo,
    const float* __restrict__ bq, const float* __restrict__ bk,
    const float* __restrict__ bv, const float* __restrict__ bo,
    const float* __restrict__ wi, const float* __restrict__ wf,
    float* __restrict__ q, float* __restrict__ k,
    float* __restrict__ v, float* __restrict__ og,
    float* __restrict__ s2)
{
    const int wave = threadIdx.x >> 6;
    const int lane = threadIdx.x & 63;
    const int rowId = blockIdx.x * 4 + wave;
    if (rowId >= 4 * H + 2) return;

    const int m = rowId >> 12;        // which matrix (0..3) when rowId < 16384
    const int r = rowId & (H - 1);

    const float* row;
    if (rowId < 4 * H) {
        const float* W = (m == 0) ? Wq : (m == 1) ? Wk : (m == 2) ? Wv : Wo;
        row = W + (size_t)r * H;
    } else {
        row = (rowId == 4 * H) ? wi : wf;
    }

    const float4* row4 = (const float4*)row;
    const float4* x4   = (const float4*)x;

    float sum = 0.0f;
    #pragma unroll
    for (int it = 0; it < ITERS; ++it) {
        const int idx = it * 64 + lane;
        float4 a = row4[idx];
        float4 b = x4[idx];
        sum += a.x * b.x + a.y * b.y + a.z * b.z + a.w * b.w;
    }
    sum = wave_reduce_sum(sum);

    if (lane == 0) {
        if (rowId < 4 * H) {
            if (m == 0)      q[r]  = sum + bq[r];
            else if (m == 1) k[r]  = (sum + bk[r]) * 0.015625f;  // 1/sqrt(4096)
            else if (m == 2) v[r]  = sum + bv[r];
            else             og[r] = sigmoidf_(sum + bo[r]);
        } else {
            s2[rowId - 4 * H] = sum;   // s2[0] = wi.x, s2[1] = wf.x (raw dots)
        }
    }
}

// Kernel 2: C = f*C_prev + (i*v[r])*k   (written to d_out), and
// u[r] = C_prev[r,:] . q  accumulated from the same loads.
__global__ __launch_bounds__(256) void c_update(
    const float* __restrict__ C_prev,
    const float* __restrict__ q, const float* __restrict__ k,
    const float* __restrict__ v, const float* __restrict__ s2,
    const float* __restrict__ bi, const float* __restrict__ bf,
    float* __restrict__ C_out, float* __restrict__ u)
{
    const int wave = threadIdx.x >> 6;
    const int lane = threadIdx.x & 63;
    const int r = blockIdx.x * 4 + wave;

    const float ig = __expf(s2[0] + bi[0]);
    const float fg = sigmoidf_(s2[1] + bf[0]);
    const float ivr = ig * v[r];

    const float4* c4 = (const float4*)(C_prev + (size_t)r * H);
    float4*       o4 = (float4*)(C_out + (size_t)r * H);
    const float4* q4 = (const float4*)q;
    const float4* k4 = (const float4*)k;

    float acc = 0.0f;
    #pragma unroll
    for (int it = 0; it < ITERS; ++it) {
        const int idx = it * 64 + lane;
        float4 c  = c4[idx];
        float4 qq = q4[idx];
        float4 kk = k4[idx];
        float4 o;
        o.x = fg * c.x + ivr * kk.x;
        o.y = fg * c.y + ivr * kk.y;
        o.z = fg * c.z + ivr * kk.z;
        o.w = fg * c.w + ivr * kk.w;
        o4[idx] = o;
        acc += c.x * qq.x + c.y * qq.y + c.z * qq.z + c.w * qq.w;
    }
    acc = wave_reduce_sum(acc);
    if (lane == 0) u[r] = acc;
}

// Kernel 3: n = f*n_prev + i*k (written out); nq = n.q; kq = k.q;
// h = og * (f*u + i*v*kq) / max(|nq|,1). Single block.
__global__ __launch_bounds__(1024) void finalize(
    const float* __restrict__ n_prev,
    const float* __restrict__ q, const float* __restrict__ k,
    const float* __restrict__ v, const float* __restrict__ og,
    const float* __restrict__ u, const float* __restrict__ s2,
    const float* __restrict__ bi, const float* __restrict__ bf,
    float* __restrict__ h, float* __restrict__ n_out)
{
    const int t = threadIdx.x;
    const int wave = t >> 6;
    const int lane = t & 63;

    const float ig = __expf(s2[0] + bi[0]);
    const float fg = sigmoidf_(s2[1] + bf[0]);

    float nq = 0.0f, kq = 0.0f;
    for (int j = t; j < H; j += 1024) {
        float kj = k[j];
        float qj = q[j];
        float nj = fg * n_prev[j] + ig * kj;
        n_out[j] = nj;
        nq += nj * qj;
        kq += kj * qj;
    }
    nq = wave_reduce_sum(nq);
    kq = wave_reduce_sum(kq);

    __shared__ float snq[16], skq[16];
    if (lane == 0) { snq[wave] = nq; skq[wave] = kq; }
    __syncthreads();
    if (t == 0) {
        float a = 0.0f, b = 0.0f;
        #pragma unroll
        for (int w = 0; w < 16; ++w) { a += snq[w]; b += skq[w]; }
        snq[0] = a; skq[0] = b;
    }
    __syncthreads();

    const float denom = fmaxf(fabsf(snq[0]), 1.0f);
    const float kqv = skq[0];
    const float inv_denom = 1.0f / denom;

    for (int j = t; j < H; j += 1024) {
        float ht = (fg * u[j] + ig * v[j] * kqv) * inv_denom;
        h[j] = og[j] * ht;
    }
}

extern "C" void kernel_launch(void* const* d_in, const int* in_sizes, int n_in,
                              void* d_out, int out_size, void* d_ws, size_t ws_size,
                              hipStream_t stream) {
    const float* x      = (const float*)d_in[0];
    // d_in[1] = h_prev (unused by mLSTM math)
    const float* C_prev = (const float*)d_in[2];
    const float* n_prev = (const float*)d_in[3];
    const float* Wq     = (const float*)d_in[4];
    const float* Wk     = (const float*)d_in[5];
    const float* Wv     = (const float*)d_in[6];
    const float* Wo     = (const float*)d_in[7];
    const float* bq     = (const float*)d_in[8];
    const float* bk     = (const float*)d_in[9];
    const float* bv     = (const float*)d_in[10];
    const float* bo     = (const float*)d_in[11];
    const float* wi     = (const float*)d_in[12];
    const float* bi     = (const float*)d_in[13];
    const float* wf     = (const float*)d_in[14];
    const float* bf     = (const float*)d_in[15];

    float* out   = (float*)d_out;
    float* h_out = out;                       // [H]
    float* C_out = out + H;                   // [H*H]
    float* n_out = out + H + (size_t)H * H;   // [H]

    float* ws = (float*)d_ws;
    float* q  = ws;
    float* k  = ws + H;
    float* v  = ws + 2 * H;
    float* og = ws + 3 * H;
    float* u  = ws + 4 * H;
    float* s2 = ws + 5 * H;                   // 2 floats

    // Kernel 1: 4*H rows + 2 dot rows, one wave per row, 4 waves per block.
    const int nrows = 4 * H + 2;
    const int blocks1 = (nrows + 3) / 4;
    gemv_all<<<blocks1, 256, 0, stream>>>(x, Wq, Wk, Wv, Wo, bq, bk, bv, bo,
                                          wi, wf, q, k, v, og, s2);

    // Kernel 2: H rows, one wave per row.
    c_update<<<H / 4, 256, 0, stream>>>(C_prev, q, k, v, s2, bi, bf, C_out, u);

    // Kernel 3: single block epilogue.
    finalize<<<1, 1024, 0, stream>>>(n_prev, q, k, v, og, u, s2, bi, bf,
                                     h_out, n_out);
}